// Round 2
// baseline (248.833 us; speedup 1.0000x reference)
//
#include <hip/hip_runtime.h>

#define MAX_SEP 512
#define T_ROWS 1025          // 2*MAX_SEP+1
#define H 160
#define H4 40                // H/4: float4 groups per row
#define B 4
#define S 256
#define TG 257               // ceil(1025/4)
#define ROWB 320             // bf16 row bytes (160 * 2)
#define HC 20                // 8-bf16 chunks per row

typedef float v8f __attribute__((ext_vector_type(8)));
typedef float v4f __attribute__((ext_vector_type(4)));
typedef unsigned short us4 __attribute__((ext_vector_type(4)));

__device__ __forceinline__ unsigned short rbf16(float f) {
    union { float f; unsigned u; } c; c.f = f;
    // round-to-nearest-even bf16
    return (unsigned short)((c.u + 0x7FFFu + ((c.u >> 16) & 1u)) >> 16);
}

// ---------------------------------------------------------------------------
// Kernel A: Wt[q][kk][h] = W[h][q*H+kk]. Makes compute_y's weight reads
// WAVE-coalesced (lane<->h, consecutive addresses). ~1 us.
// ---------------------------------------------------------------------------
__global__ __launch_bounds__(256) void transpose_w(const float* __restrict__ W,
                                                   float* __restrict__ Wt) {
    int g = blockIdx.x * 256 + threadIdx.x;       // 4*H*H = 102400
    if (g >= 4 * H * H) return;
    int h  = g % H;
    int kk = (g / H) % H;
    int q  = g / (H * H);
    Wt[g] = W[h * (4 * H) + q * H + kk];          // write coalesced over h
}

// ---------------------------------------------------------------------------
// Kernel B: Y[q][t][h] = bf16(sum_kk pe_q[t][kk]*Wt[q][kk][h] + b)
// 4h x 4t register tile, float4 loads both streams. ~3 us (verified round 1:
// 10x vmem-instr reduction vs v1 moved dur_us by 0 -> this kernel is minor).
// ---------------------------------------------------------------------------
__global__ __launch_bounds__(256) void compute_y(
        const float* __restrict__ pe0, const float* __restrict__ pe1,
        const float* __restrict__ pe2, const float* __restrict__ pe3,
        const float* __restrict__ Wt,  const float* __restrict__ bias,
        unsigned short* __restrict__ Y) {
    int e = blockIdx.x * 256 + threadIdx.x;       // over (q, tg, h4)
    if (e >= 4 * TG * H4) return;                 // 41120 threads, 161 blocks
    int h4 = e % H4;
    int tg = (e / H4) % TG;
    int q  = e / (H4 * TG);
    const float* pe = (q == 0) ? pe0 : (q == 1) ? pe1 : (q == 2) ? pe2 : pe3;

    int t0 = tg * 4;
    int t1 = min(t0 + 1, T_ROWS - 1);             // clamp reads; stores guarded
    int t2 = min(t0 + 2, T_ROWS - 1);
    int t3 = min(t0 + 3, T_ROWS - 1);
    const v4f* p0 = (const v4f*)(pe + (size_t)t0 * H);
    const v4f* p1 = (const v4f*)(pe + (size_t)t1 * H);
    const v4f* p2 = (const v4f*)(pe + (size_t)t2 * H);
    const v4f* p3 = (const v4f*)(pe + (size_t)t3 * H);
    const float* wt = Wt + (size_t)q * H * H + h4 * 4;

    v4f a0 = 0.f, a1 = 0.f, a2 = 0.f, a3 = 0.f;   // [t] x 4h accumulators
#pragma unroll 4
    for (int kc = 0; kc < H4; ++kc) {
        const float* wk = wt + (size_t)(4 * kc) * H;
        v4f w0 = *(const v4f*)(wk);               // kk = 4kc+0, h4*4..+3
        v4f w1 = *(const v4f*)(wk + H);           // kk = 4kc+1
        v4f w2 = *(const v4f*)(wk + 2 * H);       // kk = 4kc+2
        v4f w3 = *(const v4f*)(wk + 3 * H);       // kk = 4kc+3
        v4f e0 = p0[kc], e1 = p1[kc], e2 = p2[kc], e3 = p3[kc];
        // sequential kk order per accumulator (matches v1 numerics)
        a0 += e0[0] * w0; a0 += e0[1] * w1; a0 += e0[2] * w2; a0 += e0[3] * w3;
        a1 += e1[0] * w0; a1 += e1[1] * w1; a1 += e1[2] * w2; a1 += e1[3] * w3;
        a2 += e2[0] * w0; a2 += e2[1] * w1; a2 += e2[2] * w2; a2 += e2[3] * w3;
        a3 += e3[0] * w0; a3 += e3[1] * w1; a3 += e3[2] * w2; a3 += e3[3] * w3;
    }
    if (q == 0) {
        v4f vb = *(const v4f*)(bias + h4 * 4);    // bias only on table 0
        a0 += vb; a1 += vb; a2 += vb; a3 += vb;
    }

    us4 r0, r1, r2, r3;
#pragma unroll
    for (int k = 0; k < 4; ++k) {
        r0[k] = rbf16(a0[k]);
        r1[k] = rbf16(a1[k]);
        r2[k] = rbf16(a2[k]);
        r3[k] = rbf16(a3[k]);
    }
    unsigned short* yq = Y + ((size_t)q * T_ROWS + t0) * H + h4 * 4;  // 8B aligned
    *(us4*)yq = r0;                                // coalesced 512 B per wave
    if (t0 + 1 < T_ROWS) *(us4*)(yq + H)     = r1;
    if (t0 + 2 < T_ROWS) *(us4*)(yq + 2 * H) = r2;
    if (t0 + 3 < T_ROWS) *(us4*)(yq + 3 * H) = r3;
}

// ---------------------------------------------------------------------------
// Kernel C: out[b,i,j,h] = ReLU(Y0[d_ss]+Y1[d_se]+Y2[d_es]+Y3[d_ee])
// v3 change: NONTEMPORAL out stores. The 167.8 MB fp32 out stream was pushed
// through L2 (4 MiB/XCD), continuously evicting the 1.3 MB Y table and turning
// L2-hit gathers (~200cy) into L3/HBM misses. `nt` stores keep Y L2-resident.
// __launch_bounds__(256,8) pins VGPR<=64 so all 8 blocks/CU stay resident
// (32 waves/CU) for gather-latency hiding. Math is bit-identical to v2.
// ---------------------------------------------------------------------------
__global__ __launch_bounds__(256, 8) void gather_add(
        const int* __restrict__ pos_s, const int* __restrict__ pos_e,
        const unsigned short* __restrict__ Y, float* __restrict__ out) {
    int blk  = blockIdx.x;            // 0..2047
    int bi   = blk >> 1;              // (b,i) row
    int half = blk & 1;
    int bb   = bi >> 8;               // / S
    int i    = bi & (S - 1);
    int tid  = threadIdx.x;

    int psi = pos_s[bb * S + i];      // broadcast -> scalar loads
    int pei = pos_e[bb * S + i];

    __shared__ int4 rows_s[S];        // per-j byte offsets into bf16 Y
    {
        int pj_s = pos_s[bb * S + tid];
        int pj_e = pos_e[bb * S + tid];
        int4 r;
        r.x = (0 * T_ROWS + psi - pj_s + MAX_SEP) * ROWB;
        r.y = (1 * T_ROWS + psi - pj_e + MAX_SEP) * ROWB;
        r.z = (2 * T_ROWS + pei - pj_s + MAX_SEP) * ROWB;
        r.w = (3 * T_ROWS + pei - pj_e + MAX_SEP) * ROWB;
        rows_s[tid] = r;
    }
    __syncthreads();

    const char* __restrict__ Yb = (const char*)Y;
    float* __restrict__ outp = out + (size_t)bi * (S * H);
    int start = half * (S * HC / 2);  // 2560 chunks per half, 10 iters of 256

#pragma unroll 2
    for (int it = 0; it < 10; ++it) {
        int c  = start + it * 256 + tid;
        int j  = c / HC;              // magic-mul
        int c8 = c - j * HC;
        int4 r4 = rows_s[j];          // ds_read_b128
        int hb = c8 << 4;             // 16 B per 8-bf16 chunk
        uint4 u0 = *(const uint4*)(Yb + (r4.x + hb));
        uint4 u1 = *(const uint4*)(Yb + (r4.y + hb));
        uint4 u2 = *(const uint4*)(Yb + (r4.z + hb));
        uint4 u3 = *(const uint4*)(Yb + (r4.w + hb));

        // dword k holds h=2k (low 16) and h=2k+1 (high 16)
        float sv[8];
        const unsigned* a0 = (const unsigned*)&u0;
        const unsigned* a1 = (const unsigned*)&u1;
        const unsigned* a2 = (const unsigned*)&u2;
        const unsigned* a3 = (const unsigned*)&u3;
#pragma unroll
        for (int k = 0; k < 4; ++k) {
            union { unsigned x; float f; } lo0, hi0, lo1, hi1, lo2, hi2, lo3, hi3;
            lo0.x = a0[k] << 16; hi0.x = a0[k] & 0xFFFF0000u;
            lo1.x = a1[k] << 16; hi1.x = a1[k] & 0xFFFF0000u;
            lo2.x = a2[k] << 16; hi2.x = a2[k] & 0xFFFF0000u;
            lo3.x = a3[k] << 16; hi3.x = a3[k] & 0xFFFF0000u;
            float slo = (lo0.f + lo1.f) + (lo2.f + lo3.f);
            float shi = (hi0.f + hi1.f) + (hi2.f + hi3.f);
            sv[2 * k]     = fmaxf(slo, 0.f);
            sv[2 * k + 1] = fmaxf(shi, 0.f);
        }
        v4f o0 = { sv[0], sv[1], sv[2], sv[3] };
        v4f o1 = { sv[4], sv[5], sv[6], sv[7] };
        float* outc = outp + (size_t)c * 8;
        __builtin_nontemporal_store(o0, (v4f*)outc);       // 16 B nt store
        __builtin_nontemporal_store(o1, (v4f*)outc + 1);   // 16 B nt store
    }
}

// ---------------------------------------------------------------------------
extern "C" void kernel_launch(void* const* d_in, const int* in_sizes, int n_in,
                              void* d_out, int out_size, void* d_ws, size_t ws_size,
                              hipStream_t stream) {
    const int*   pos_s = (const int*)d_in[0];
    const int*   pos_e = (const int*)d_in[1];
    const float* pe_ss = (const float*)d_in[2];
    const float* pe_se = (const float*)d_in[3];
    const float* pe_es = (const float*)d_in[4];
    const float* pe_ee = (const float*)d_in[5];
    const float* W     = (const float*)d_in[6];
    const float* bias  = (const float*)d_in[7];
    float* out = (float*)d_out;

    // workspace: Wt fp32 [4*H*H] (409,600 B) then Y bf16 (1,312,000 B)
    float* Wt = (float*)d_ws;
    unsigned short* Y = (unsigned short*)(Wt + 4 * H * H);

    transpose_w<<<(4 * H * H + 255) / 256, 256, 0, stream>>>(W, Wt);
    compute_y<<<(4 * TG * H4 + 255) / 256, 256, 0, stream>>>(
        pe_ss, pe_se, pe_es, pe_ee, Wt, bias, Y);
    gather_add<<<2 * B * S, 256, 0, stream>>>(pos_s, pos_e, Y, out);
}

// Round 4
// 211.483 us; speedup vs baseline: 1.1766x; 1.1766x over previous
//
#include <hip/hip_runtime.h>

#define MAX_SEP 512
#define T_ROWS 1025          // 2*MAX_SEP+1
#define H 160
#define H4 40                // H/4: float4 groups per row
#define B 4
#define S 256
#define TG 257               // ceil(1025/4)
#define ROWB 320             // bf16 row bytes (160 * 2)
#define HC 20                // 8-bf16 chunks per row

typedef float v8f __attribute__((ext_vector_type(8)));
typedef float v4f __attribute__((ext_vector_type(4)));
typedef unsigned short us4 __attribute__((ext_vector_type(4)));

__device__ __forceinline__ unsigned short rbf16(float f) {
    union { float f; unsigned u; } c; c.f = f;
    // round-to-nearest-even bf16
    return (unsigned short)((c.u + 0x7FFFu + ((c.u >> 16) & 1u)) >> 16);
}

// ---------------------------------------------------------------------------
// Kernel A: Wt[q][kk][h] = W[h][q*H+kk]. Makes compute_y's weight reads
// WAVE-coalesced (lane<->h, consecutive addresses). ~1 us.
// ---------------------------------------------------------------------------
__global__ __launch_bounds__(256) void transpose_w(const float* __restrict__ W,
                                                   float* __restrict__ Wt) {
    int g = blockIdx.x * 256 + threadIdx.x;       // 4*H*H = 102400
    if (g >= 4 * H * H) return;
    int h  = g % H;
    int kk = (g / H) % H;
    int q  = g / (H * H);
    Wt[g] = W[h * (4 * H) + q * H + kk];          // write coalesced over h
}

// ---------------------------------------------------------------------------
// Kernel B: Y[q][t][h] = bf16(sum_kk pe_q[t][kk]*Wt[q][kk][h] + b)
// 4h x 4t register tile, float4 loads both streams. ~3 us.
// ---------------------------------------------------------------------------
__global__ __launch_bounds__(256) void compute_y(
        const float* __restrict__ pe0, const float* __restrict__ pe1,
        const float* __restrict__ pe2, const float* __restrict__ pe3,
        const float* __restrict__ Wt,  const float* __restrict__ bias,
        unsigned short* __restrict__ Y) {
    int e = blockIdx.x * 256 + threadIdx.x;       // over (q, tg, h4)
    if (e >= 4 * TG * H4) return;                 // 41120 threads, 161 blocks
    int h4 = e % H4;
    int tg = (e / H4) % TG;
    int q  = e / (H4 * TG);
    const float* pe = (q == 0) ? pe0 : (q == 1) ? pe1 : (q == 2) ? pe2 : pe3;

    int t0 = tg * 4;
    int t1 = min(t0 + 1, T_ROWS - 1);             // clamp reads; stores guarded
    int t2 = min(t0 + 2, T_ROWS - 1);
    int t3 = min(t0 + 3, T_ROWS - 1);
    const v4f* p0 = (const v4f*)(pe + (size_t)t0 * H);
    const v4f* p1 = (const v4f*)(pe + (size_t)t1 * H);
    const v4f* p2 = (const v4f*)(pe + (size_t)t2 * H);
    const v4f* p3 = (const v4f*)(pe + (size_t)t3 * H);
    const float* wt = Wt + (size_t)q * H * H + h4 * 4;

    v4f a0 = 0.f, a1 = 0.f, a2 = 0.f, a3 = 0.f;   // [t] x 4h accumulators
#pragma unroll 4
    for (int kc = 0; kc < H4; ++kc) {
        const float* wk = wt + (size_t)(4 * kc) * H;
        v4f w0 = *(const v4f*)(wk);               // kk = 4kc+0, h4*4..+3
        v4f w1 = *(const v4f*)(wk + H);           // kk = 4kc+1
        v4f w2 = *(const v4f*)(wk + 2 * H);       // kk = 4kc+2
        v4f w3 = *(const v4f*)(wk + 3 * H);       // kk = 4kc+3
        v4f e0 = p0[kc], e1 = p1[kc], e2 = p2[kc], e3 = p3[kc];
        // sequential kk order per accumulator (matches v1 numerics)
        a0 += e0[0] * w0; a0 += e0[1] * w1; a0 += e0[2] * w2; a0 += e0[3] * w3;
        a1 += e1[0] * w0; a1 += e1[1] * w1; a1 += e1[2] * w2; a1 += e1[3] * w3;
        a2 += e2[0] * w0; a2 += e2[1] * w1; a2 += e2[2] * w2; a2 += e2[3] * w3;
        a3 += e3[0] * w0; a3 += e3[1] * w1; a3 += e3[2] * w2; a3 += e3[3] * w3;
    }
    if (q == 0) {
        v4f vb = *(const v4f*)(bias + h4 * 4);    // bias only on table 0
        a0 += vb; a1 += vb; a2 += vb; a3 += vb;
    }

    us4 r0, r1, r2, r3;
#pragma unroll
    for (int k = 0; k < 4; ++k) {
        r0[k] = rbf16(a0[k]);
        r1[k] = rbf16(a1[k]);
        r2[k] = rbf16(a2[k]);
        r3[k] = rbf16(a3[k]);
    }
    unsigned short* yq = Y + ((size_t)q * T_ROWS + t0) * H + h4 * 4;  // 8B aligned
    *(us4*)yq = r0;                                // coalesced 512 B per wave
    if (t0 + 1 < T_ROWS) *(us4*)(yq + H)     = r1;
    if (t0 + 2 < T_ROWS) *(us4*)(yq + 2 * H) = r2;
    if (t0 + 3 < T_ROWS) *(us4*)(yq + 3 * H) = r3;
}

// ---------------------------------------------------------------------------
// Kernel C: out[b,i,j,h] = ReLU(Y0[d_ss]+Y1[d_se]+Y2[d_es]+Y3[d_ee])
// Round-0/1 form. Round-2 lesson (measured): the 167.8 MB out stream is
// ABSORBED BY L3 (256 MB) with normal cached stores; nontemporal stores
// forced it to HBM and cost +23 us. Y gathers are L2-hit already.
// ---------------------------------------------------------------------------
__global__ __launch_bounds__(256) void gather_add(
        const int* __restrict__ pos_s, const int* __restrict__ pos_e,
        const unsigned short* __restrict__ Y, float* __restrict__ out) {
    int blk  = blockIdx.x;            // 0..2047
    int bi   = blk >> 1;              // (b,i) row
    int half = blk & 1;
    int bb   = bi >> 8;               // / S
    int i    = bi & (S - 1);
    int tid  = threadIdx.x;

    int psi = pos_s[bb * S + i];      // broadcast -> scalar loads
    int pei = pos_e[bb * S + i];

    __shared__ int4 rows_s[S];        // per-j byte offsets into bf16 Y
    {
        int pj_s = pos_s[bb * S + tid];
        int pj_e = pos_e[bb * S + tid];
        int4 r;
        r.x = (0 * T_ROWS + psi - pj_s + MAX_SEP) * ROWB;
        r.y = (1 * T_ROWS + psi - pj_e + MAX_SEP) * ROWB;
        r.z = (2 * T_ROWS + pei - pj_s + MAX_SEP) * ROWB;
        r.w = (3 * T_ROWS + pei - pj_e + MAX_SEP) * ROWB;
        rows_s[tid] = r;
    }
    __syncthreads();

    const char* __restrict__ Yb = (const char*)Y;
    float* __restrict__ outp = out + (size_t)bi * (S * H);
    int start = half * (S * HC / 2);  // 2560 chunks per half, 10 iters of 256

#pragma unroll 2
    for (int it = 0; it < 10; ++it) {
        int c  = start + it * 256 + tid;
        int j  = c / HC;              // magic-mul
        int c8 = c - j * HC;
        int4 r4 = rows_s[j];          // ds_read_b128
        int hb = c8 << 4;             // 16 B per 8-bf16 chunk
        uint4 u0 = *(const uint4*)(Yb + (r4.x + hb));
        uint4 u1 = *(const uint4*)(Yb + (r4.y + hb));
        uint4 u2 = *(const uint4*)(Yb + (r4.z + hb));
        uint4 u3 = *(const uint4*)(Yb + (r4.w + hb));

        v8f s;
        const unsigned* a0 = (const unsigned*)&u0;
        const unsigned* a1 = (const unsigned*)&u1;
        const unsigned* a2 = (const unsigned*)&u2;
        const unsigned* a3 = (const unsigned*)&u3;
#pragma unroll
        for (int k = 0; k < 4; ++k) {
            union { unsigned x; float f; } lo0, hi0, lo1, hi1, lo2, hi2, lo3, hi3;
            lo0.x = a0[k] << 16; hi0.x = a0[k] & 0xFFFF0000u;
            lo1.x = a1[k] << 16; hi1.x = a1[k] & 0xFFFF0000u;
            lo2.x = a2[k] << 16; hi2.x = a2[k] & 0xFFFF0000u;
            lo3.x = a3[k] << 16; hi3.x = a3[k] & 0xFFFF0000u;
            float slo = (lo0.f + lo1.f) + (lo2.f + lo3.f);
            float shi = (hi0.f + hi1.f) + (hi2.f + hi3.f);
            s[2 * k]     = fmaxf(slo, 0.f);
            s[2 * k + 1] = fmaxf(shi, 0.f);
        }
        *(v8f*)(outp + (size_t)c * 8) = s;   // 32 B coalesced (2x dwordx4)
    }
}

// ---------------------------------------------------------------------------
extern "C" void kernel_launch(void* const* d_in, const int* in_sizes, int n_in,
                              void* d_out, int out_size, void* d_ws, size_t ws_size,
                              hipStream_t stream) {
    const int*   pos_s = (const int*)d_in[0];
    const int*   pos_e = (const int*)d_in[1];
    const float* pe_ss = (const float*)d_in[2];
    const float* pe_se = (const float*)d_in[3];
    const float* pe_es = (const float*)d_in[4];
    const float* pe_ee = (const float*)d_in[5];
    const float* W     = (const float*)d_in[6];
    const float* bias  = (const float*)d_in[7];
    float* out = (float*)d_out;

    // workspace: Wt fp32 [4*H*H] (409,600 B) then Y bf16 (1,312,000 B)
    float* Wt = (float*)d_ws;
    unsigned short* Y = (unsigned short*)(Wt + 4 * H * H);

    transpose_w<<<(4 * H * H + 255) / 256, 256, 0, stream>>>(W, Wt);
    compute_y<<<(4 * TG * H4 + 255) / 256, 256, 0, stream>>>(
        pe_ss, pe_se, pe_es, pe_ee, Wt, bias, Y);
    gather_add<<<2 * B * S, 256, 0, stream>>>(pos_s, pos_e, Y, out);
}